// Round 15
// baseline (111.841 us; speedup 1.0000x reference)
//
#include <hip/hip_runtime.h>

// KDA delta-rule state update, B=H=32, K=V=256, fp32.
// out[k,v] = g[k]*S[k,v] + cb[k]*(val[v] - kt[v]),
//   w[k] = g[k]*key[k], cb[k] = beta*key[k], kt[v] = sum_k w[k]*S[k,v].
//
// R15: ONE-WAVE BLOCKS. Same per-lane layout as R10/R14 (lane (r8,c8)
// owns 32 rows x one f32x4 col, 128B chunks, in-wave butterfly kt) but
// block = 64 threads = 1 wave -> ZERO barriers (same-wave LDS visibility
// needs only lgkmcnt), ~12 independently-scheduled blocks/CU, fine-grain
// completion staggering -> steadier read/write mix at the memory system.
// Prologue keeps R14's issue order (scalars -> tiles -> stage).

#define KD 256
#define VD 256
#define VD4 (VD / 4)   // 64 f32x4 per row

typedef float f32x4 __attribute__((ext_vector_type(4)));

__global__ __launch_bounds__(64, 2)
void kda_update_kernel(const float* __restrict__ state,
                       const float* __restrict__ keys,
                       const float* __restrict__ values,
                       const float* __restrict__ gates,
                       const float* __restrict__ beta,
                       float* __restrict__ out)
{
    const int bid = blockIdx.x;
    const int bh  = bid >> 3;           // (b,h) tile
    const int cg  = bid & 7;            // column group (8 f32x4 cols)
    const size_t toff = (size_t)bh * (KD * VD);
    const f32x4* __restrict__ S4 = (const f32x4*)(state + toff);
    f32x4* __restrict__ O4 = (f32x4*)(out + toff);

    __shared__ float s_g[KD];   // alpha        (per-wave private: 1-wave block)
    __shared__ float s_w[KD];   // alpha*key
    __shared__ float s_c[KD];   // beta*key

    const int lane = threadIdx.x;       // 0..63
    const int r8   = lane >> 3;         // row residue 0..7
    const int c8   = lane & 7;          // f32x4 col within group
    const int col  = cg * 8 + c8;       // this lane's f32x4 column

    // ---- (a) scalar loads FIRST (oldest in the in-order VMEM queue):
    //      each lane covers 4 rows of g/k ----
    const f32x4 g4 = ((const f32x4*)(gates + (size_t)bh * KD))[lane];
    const f32x4 k4 = ((const f32x4*)(keys  + (size_t)bh * KD))[lane];
    const float bb = beta[bh];
    __builtin_amdgcn_sched_barrier(0);   // pin: scalars issued before tiles

    // ---- (b) issue all 32 tile loads (128B chunks, rows r8+8j) ----
    f32x4 s[32];
#pragma unroll
    for (int j = 0; j < 32; ++j)
        s[j] = __builtin_nontemporal_load(&S4[(size_t)(r8 + 8 * j) * VD4 + col]);
    __builtin_amdgcn_sched_barrier(0);   // pin: tiles issued before staging

    // ---- (c) stage scalars (waits vmcnt(32): tile loads stay in flight) ----
    {
        const int r = lane * 4;
        s_g[r + 0] = g4.x; s_w[r + 0] = g4.x * k4.x; s_c[r + 0] = bb * k4.x;
        s_g[r + 1] = g4.y; s_w[r + 1] = g4.y * k4.y; s_c[r + 1] = bb * k4.y;
        s_g[r + 2] = g4.z; s_w[r + 2] = g4.z * k4.z; s_c[r + 2] = bb * k4.z;
        s_g[r + 3] = g4.w; s_w[r + 3] = g4.w * k4.w; s_c[r + 3] = bb * k4.w;
    }
    // ---- (d) same-wave LDS visibility: lgkmcnt only, NO barrier ----
    asm volatile("s_waitcnt lgkmcnt(0)" ::: "memory");

    // ---- in-lane kt partial over this lane's 32 rows ----
    f32x4 p = (f32x4)(0.f);
#pragma unroll
    for (int j = 0; j < 32; ++j) {
        const float w = s_w[r8 + 8 * j];   // 8 words, broadcast over c8: free
        p.x = fmaf(w, s[j].x, p.x);
        p.y = fmaf(w, s[j].y, p.y);
        p.z = fmaf(w, s[j].z, p.z);
        p.w = fmaf(w, s[j].w, p.w);
    }

    // ---- in-wave reduce over r8 (lane bits 3,4,5): 3 butterfly rounds ----
#pragma unroll
    for (int m = 8; m <= 32; m <<= 1) {
        p.x += __shfl_xor(p.x, m, 64);
        p.y += __shfl_xor(p.y, m, 64);
        p.z += __shfl_xor(p.z, m, 64);
        p.w += __shfl_xor(p.w, m, 64);
    }

    const f32x4 vv = ((const f32x4*)(values + (size_t)bh * VD))[col];
    f32x4 d;
    d.x = vv.x - p.x; d.y = vv.y - p.y;
    d.z = vv.z - p.z; d.w = vv.w - p.w;

    // ---- output: straight from registers, NT stores ----
#pragma unroll
    for (int j = 0; j < 32; ++j) {
        const int r = r8 + 8 * j;
        const float g  = s_g[r];
        const float cb = s_c[r];
        f32x4 o;
        o.x = fmaf(g, s[j].x, cb * d.x);
        o.y = fmaf(g, s[j].y, cb * d.y);
        o.z = fmaf(g, s[j].z, cb * d.z);
        o.w = fmaf(g, s[j].w, cb * d.w);
        __builtin_nontemporal_store(o, &O4[(size_t)r * VD4 + col]);
    }
}

extern "C" void kernel_launch(void* const* d_in, const int* in_sizes, int n_in,
                              void* d_out, int out_size, void* d_ws, size_t ws_size,
                              hipStream_t stream) {
    const float* state  = (const float*)d_in[0];
    const float* keys   = (const float*)d_in[1];
    const float* values = (const float*)d_in[2];
    const float* gates  = (const float*)d_in[3];
    const float* beta   = (const float*)d_in[4];
    float* out = (float*)d_out;

    dim3 grid(32 * 32 * 8);   // (b,h) x 8 column groups, 1 wave each
    dim3 block(64);
    hipLaunchKernelGGL(kda_update_kernel, grid, block, 0, stream,
                       state, keys, values, gates, beta, out);
}